// Round 11
// baseline (247.954 us; speedup 1.0000x reference)
//
#include <hip/hip_runtime.h>

// B=8, L=1024, H=1024, NH=16, HD=64. fp32 I/O, bf16 MFMA internals.
// Pipeline: cvt3     : x,w_qkv,w_out fp32 -> bf16                  (~13 us)
//           gemm16<0>: qk = x@w_qkv^T cols<2048; V scatters to Vt  (51.5 GF)
//           attn     : no-max softmax flash attn, S^T trick        (34.4 GF)
//           gemm16<1>: out = O@w_out^T + b_out (fp32 out)          (17.2 GF)
// R11 (attn VALU diet — attn is VALU-throughput-bound per R5-R10 record):
//  - row-sums via MFMA: Ones_acc = P * ones^T (const bf16 1.0 B-frag);
//    reg r = rowsum(q=quad*4+r) in all lanes -> no VALU adds, no shuffles.
//  - pack via gfx950 v_cvt_pk_bf16_f32 (1 op / 2 elems, has_builtin-guarded).

typedef short s16x8 __attribute__((ext_vector_type(8)));
typedef float f32x4 __attribute__((ext_vector_type(4)));
typedef unsigned int u32x2 __attribute__((ext_vector_type(2)));
typedef unsigned int u32x4 __attribute__((ext_vector_type(4)));

__device__ __forceinline__ unsigned short f2bf(float f) {   // RNE
    union { float f; unsigned u; } c; c.f = f;
    return (unsigned short)((c.u + 0x7FFFu + ((c.u >> 16) & 1u)) >> 16);
}
// pack 2 floats -> 2 bf16, low=a high=b. Native single-op on gfx950, else perm.
__device__ __forceinline__ unsigned pack2bf(float a, float b) {
#if __has_builtin(__builtin_amdgcn_cvt_pk_bf16_f32)
    typedef __bf16 bf16x2_t __attribute__((ext_vector_type(2)));
    bf16x2_t v = __builtin_amdgcn_cvt_pk_bf16_f32(a, b);
    unsigned r; __builtin_memcpy(&r, &v, 4); return r;
#else
    union { float f; unsigned u; } ca, cb; ca.f = a; cb.f = b;
    return __builtin_amdgcn_perm(cb.u + 0x8000u, ca.u + 0x8000u, 0x07060302u);
#endif
}

#define GLOAD_LDS(g, l) __builtin_amdgcn_global_load_lds( \
    (const __attribute__((address_space(1))) void*)(g),   \
    (__attribute__((address_space(3))) void*)(l), 16, 0, 0)

// ---------------------------------------------------------------------------
// fp32 -> bf16 convert for the three input tensors.
// ---------------------------------------------------------------------------
__global__ __launch_bounds__(256) void cvt3(
    const float* __restrict__ s0, unsigned short* __restrict__ d0, int n0,
    const float* __restrict__ s1, unsigned short* __restrict__ d1, int n1,
    const float* __restrict__ s2, unsigned short* __restrict__ d2, int n2)
{
    long i = ((long)blockIdx.x * 256 + threadIdx.x) * 8;
    const float* s; unsigned short* d; long off;
    if (i < n0)                  { s = s0; d = d0; off = i; }
    else if (i < (long)n0 + n1)  { s = s1; d = d1; off = i - n0; }
    else                         { s = s2; d = d2; off = i - n0 - n1; }
    f32x4 a = *(const f32x4*)(s + off);
    f32x4 b = *(const f32x4*)(s + off + 4);
    u32x4 r;
    r[0] = pack2bf(a[0], a[1]); r[1] = pack2bf(a[2], a[3]);
    r[2] = pack2bf(b[0], b[1]); r[3] = pack2bf(b[2], b[3]);
    *(u32x4*)(d + off) = r;
}

// ---------------------------------------------------------------------------
// GEMM: C[M,N] = A[M,K]*B[N,K]^T, bf16 in, fp32 accum. 128x128 tile, BK=64,
// global_load_lds dwordx4. LDS [128][64] elems, XOR swizzle: logical 16B
// chunk q of row r at physical chunk q ^ (r&7) -> 2-way on banks (free).
// EPI=0: cols<1024 (Q) -> Cq bf16 scaled by 0.125*log2(e) (softmax prefold);
//        cols 1024..2047 (K) -> Cq bf16 unscaled; cols>=2048 (V) packed-
//        scatter to Cv = Vt[(b*16+h)*64+d][l] bf16.
// EPI=1: Cf fp32 + bias.
// ---------------------------------------------------------------------------
template<int EPI>
__global__ __launch_bounds__(256) void gemm16(
    const unsigned short* __restrict__ A, const unsigned short* __restrict__ Bm,
    unsigned short* __restrict__ Cq, unsigned short* __restrict__ Cv,
    float* __restrict__ Cf, const float* __restrict__ bias,
    int N, int K)
{
    __shared__ unsigned short As[128 * 64];
    __shared__ unsigned short Bs[128 * 64];
    const int tid = threadIdx.x, lane = tid & 63, wave = tid >> 6;
    const int quad = lane >> 4, l16 = lane & 15;
    const int wm = (wave >> 1) * 64, wn = (wave & 1) * 64;
    const int m0 = blockIdx.y * 128, n0 = blockIdx.x * 128;

    const int prow = tid >> 3;
    const int qch  = (tid & 7) ^ (prow & 7);
    const unsigned short* gA[4];
    const unsigned short* gB[4];
    #pragma unroll
    for (int c = 0; c < 4; ++c) {
        gA[c] = A + (size_t)(m0 + c * 32 + prow) * K + qch * 8;
        gB[c] = Bm + (size_t)(n0 + c * 32 + prow) * K + qch * 8;
    }
    const int sw = l16 & 7;   // frag-read swizzle

    f32x4 acc[4][4] = {};
    for (int k0 = 0; k0 < K; k0 += 64) {
        __syncthreads();
        #pragma unroll
        for (int c = 0; c < 4; ++c) {
            GLOAD_LDS(gA[c], As + (c * 256 + tid) * 8);
            GLOAD_LDS(gB[c], Bs + (c * 256 + tid) * 8);
            gA[c] += 64; gB[c] += 64;
        }
        __syncthreads();
        #pragma unroll
        for (int s = 0; s < 2; ++s) {
            s16x8 af[4], bf[4];
            const int pc = ((s * 4 + quad) ^ sw) * 8;
            #pragma unroll
            for (int i = 0; i < 4; ++i)
                af[i] = *(const s16x8*)(As + (wm + i * 16 + l16) * 64 + pc);
            #pragma unroll
            for (int j = 0; j < 4; ++j)
                bf[j] = *(const s16x8*)(Bs + (wn + j * 16 + l16) * 64 + pc);
            #pragma unroll
            for (int i = 0; i < 4; ++i)
                #pragma unroll
                for (int j = 0; j < 4; ++j)
                    acc[i][j] = __builtin_amdgcn_mfma_f32_16x16x32_bf16(af[i], bf[j], acc[i][j], 0, 0, 0);
        }
    }

    // epilogue: C/D layout col=lane&15, row=quad*4+reg
    if (EPI == 1) {
        #pragma unroll
        for (int j = 0; j < 4; ++j) {
            int col = n0 + wn + j * 16 + l16;
            float bv = bias[col];
            #pragma unroll
            for (int i = 0; i < 4; ++i)
                #pragma unroll
                for (int r = 0; r < 4; ++r)
                    Cf[(size_t)(m0 + wm + i * 16 + quad * 4 + r) * N + col] = acc[i][j][r] + bv;
        }
    } else if (n0 < 2048) {
        // Q region: prefold softmax scale (1/8) and log2(e) for native exp2
        const float qs = (n0 < 1024) ? 0.18033688f : 1.0f;   // 0.125*log2(e)
        #pragma unroll
        for (int j = 0; j < 4; ++j) {
            int col = n0 + wn + j * 16 + l16;
            #pragma unroll
            for (int i = 0; i < 4; ++i)
                #pragma unroll
                for (int r = 0; r < 4; ++r)
                    Cq[(size_t)(m0 + wm + i * 16 + quad * 4 + r) * 2048 + col] = f2bf(acc[i][j][r] * qs);
        }
    } else {
        // V region: lane's r=0..3 are 4 consecutive l -> one 8B packed store
        #pragma unroll
        for (int j = 0; j < 4; ++j) {
            int dcol = n0 + wn + j * 16 + l16 - 2048;
            int hh = dcol >> 6, dd = dcol & 63;
            #pragma unroll
            for (int i = 0; i < 4; ++i) {
                int row = m0 + wm + i * 16 + quad * 4;
                int bb = row >> 10, l = row & 1023;
                u32x2 pw;
                pw[0] = pack2bf(acc[i][j][0], acc[i][j][1]);
                pw[1] = pack2bf(acc[i][j][2], acc[i][j][3]);
                *(u32x2*)(Cv + (size_t)((bb * 16 + hh) * 64 + dd) * 1024 + l) = pw;
            }
        }
    }
}

// ---------------------------------------------------------------------------
// Flash attention, no-max softmax (Q pre-scaled by 0.125*log2e -> bare exp2),
// S^T trick with kv-permuted K staging so P's packed C-layout registers are
// directly the PV A-fragments (no P LDS round-trip).
// K staging permutation: LDS row rho = 16t+4u+r holds kv = 32(t>>1)+8u+4(t&1)+r.
// Row-sums: Ones_acc = P*ones^T MFMA (reg r = rowsum(q=quad*4+r), all lanes).
// 64 q-rows/block, grid (16 qtile, 128 bh) = 8 blocks/CU. LDS 16.4 KB.
// ---------------------------------------------------------------------------
__global__ __launch_bounds__(256) void attn(
    const unsigned short* __restrict__ qk, const unsigned short* __restrict__ Vt,
    unsigned short* __restrict__ O)
{
    __shared__ unsigned short Ks[64 * 64];   // [rho][d] kv-permuted, swizzled
    __shared__ unsigned short Vs[64 * 64];   // [d][kv]  natural, swizzled

    const int bh = blockIdx.y, b = bh >> 4, hh = bh & 15;
    const int q0 = blockIdx.x * 64;
    const int tid = threadIdx.x, lane = tid & 63, wave = tid >> 6;
    const int quad = lane >> 4, l16 = lane & 15;

    // Q frags direct from global: B-operand, n=q=wave*16+l16, k=s*32+quad*8
    const unsigned short* qrow =
        qk + (size_t)(b * 1024 + q0 + wave * 16 + l16) * 2048 + hh * 64;
    s16x8 qf[2];
    qf[0] = *(const s16x8*)(qrow + quad * 8);
    qf[1] = *(const s16x8*)(qrow + 32 + quad * 8);

    // all-ones bf16 B-frag for the rowsum MFMA (register constant)
    s16x8 onef;
    #pragma unroll
    for (int e = 0; e < 8; ++e) onef[e] = (short)0x3F80;

    // Staging: wave covers LDS rows rho0 = wave*16+rl and rho1 = rho0+8
    // (rl = lane>>3); chunk swizzle qc = (lane&7) ^ (rho&7), rho&7 == rl.
    // K source rows are the PERMUTED kv for each rho (t = wave for both).
    const int rl = lane >> 3;
    const int qc = (lane & 7) ^ rl;
    const int u0 = rl >> 2, r0 = rl & 3;
    const int kvbase = 32 * (wave >> 1) + 4 * (wave & 1) + r0;
    const int kv0 = kvbase + 8 * u0;          // for LDS row wave*16 + rl
    const int kv1 = kvbase + 8 * (2 + u0);    // for LDS row wave*16 + 8 + rl
    const unsigned short* srcK0 = qk + (size_t)(b * 1024 + kv0) * 2048 + 1024 + hh * 64 + qc * 8;
    const unsigned short* srcK1 = qk + (size_t)(b * 1024 + kv1) * 2048 + 1024 + hh * 64 + qc * 8;
    const unsigned short* srcV0 = Vt + (size_t)(bh * 64 + wave * 16 + rl) * 1024 + qc * 8;
    const unsigned short* srcV1 = Vt + (size_t)(bh * 64 + wave * 16 + 8 + rl) * 1024 + qc * 8;
    unsigned short* dK0 = Ks + (wave * 16 + rl) * 64 + (lane & 7) * 8;
    unsigned short* dK1 = Ks + (wave * 16 + 8 + rl) * 64 + (lane & 7) * 8;
    unsigned short* dV0 = Vs + (wave * 16 + rl) * 64 + (lane & 7) * 8;
    unsigned short* dV1 = Vs + (wave * 16 + 8 + rl) * 64 + (lane & 7) * 8;

    const int sw = l16 & 7;   // frag-read swizzle

    f32x4 Oacc[4] = {};
    f32x4 Ones = {};          // rowsum accumulator (P * ones^T)

    for (int kv = 0; kv < 1024; kv += 64) {
        __syncthreads();
        GLOAD_LDS(srcK0, dK0);
        GLOAD_LDS(srcK1, dK1);
        GLOAD_LDS(srcV0, dV0);
        GLOAD_LDS(srcV1, dV1);
        srcK0 += (size_t)64 * 2048; srcK1 += (size_t)64 * 2048;
        srcV0 += 64; srcV1 += 64;
        __syncthreads();   // vmcnt(0) drain -> K,V in LDS

        // S^T = K Q^T : tile t rows = permuted kv, col q = l16
        f32x4 Sacc[4] = {};
        #pragma unroll
        for (int t = 0; t < 4; ++t) {
            #pragma unroll
            for (int s = 0; s < 2; ++s) {
                s16x8 kf = *(const s16x8*)(Ks + (t * 16 + l16) * 64 + ((s * 4 + quad) ^ sw) * 8);
                Sacc[t] = __builtin_amdgcn_mfma_f32_16x16x32_bf16(kf, qf[s], Sacc[t], 0, 0, 0);
            }
        }
        // p = 2^s; pack pairs (these ARE the PV A-frags); no VALU row-sums
        unsigned upw[4][2];
        #pragma unroll
        for (int t = 0; t < 4; ++t) {
            float p0 = __builtin_amdgcn_exp2f(Sacc[t][0]);
            float p1 = __builtin_amdgcn_exp2f(Sacc[t][1]);
            float p2 = __builtin_amdgcn_exp2f(Sacc[t][2]);
            float p3 = __builtin_amdgcn_exp2f(Sacc[t][3]);
            upw[t][0] = pack2bf(p0, p1);
            upw[t][1] = pack2bf(p2, p3);
        }
        // O += P V^T and rowsum += P ones^T
        #pragma unroll
        for (int s = 0; s < 2; ++s) {
            u32x4 aw;
            aw[0] = upw[2 * s][0];     aw[1] = upw[2 * s][1];
            aw[2] = upw[2 * s + 1][0]; aw[3] = upw[2 * s + 1][1];
            s16x8 pf;
            __builtin_memcpy(&pf, &aw, 16);
            Ones = __builtin_amdgcn_mfma_f32_16x16x32_bf16(pf, onef, Ones, 0, 0, 0);
            #pragma unroll
            for (int jd = 0; jd < 4; ++jd) {
                s16x8 vf = *(const s16x8*)(Vs + (jd * 16 + l16) * 64 + ((s * 4 + quad) ^ sw) * 8);
                Oacc[jd] = __builtin_amdgcn_mfma_f32_16x16x32_bf16(pf, vf, Oacc[jd], 0, 0, 0);
            }
        }
    }

    // normalize + write: Ones[r] = rowsum(q = quad*4+r), identical in all lanes
    float rinv[4];
    #pragma unroll
    for (int r = 0; r < 4; ++r) rinv[r] = 1.0f / Ones[r];
    #pragma unroll
    for (int j = 0; j < 4; ++j)
        #pragma unroll
        for (int r = 0; r < 4; ++r) {
            int row = q0 + wave * 16 + quad * 4 + r;
            int col = hh * 64 + j * 16 + l16;
            O[(size_t)(b * 1024 + row) * 1024 + col] = f2bf(Oacc[j][r] * rinv[r]);
        }
}

extern "C" void kernel_launch(void* const* d_in, const int* in_sizes, int n_in,
                              void* d_out, int out_size, void* d_ws, size_t ws_size,
                              hipStream_t stream) {
    const float* x     = (const float*)d_in[0];   // [8192,1024]
    const float* w_qkv = (const float*)d_in[1];   // [3072,1024]
    const float* w_out = (const float*)d_in[2];   // [1024,1024]
    const float* b_out = (const float*)d_in[3];   // [1024]
    float* out = (float*)d_out;                   // [8192,1024] fp32

    const int nx = 8192 * 1024, nwq = 3072 * 1024, nwo = 1024 * 1024;
    unsigned short* xb  = (unsigned short*)d_ws;          // 16.8 MB (dead after gemm1)
    unsigned short* wqb = xb + nx;                        //  6.3 MB
    unsigned short* wob = wqb + nwq;                      //  2.1 MB
    unsigned short* qkb = wob + nwo;                      // [8192,2048] Q|K, 33.6 MB
    unsigned short* Vt  = qkb + (size_t)8192 * 2048;      // [128*64,1024], 16.8 MB
    unsigned short* Ob  = xb;                             // alias: xb dead after gemm1

    dim3 blk(256);
    cvt3<<<6144, blk, 0, stream>>>(x, xb, nx, w_qkv, wqb, nwq, w_out, wob, nwo);
    gemm16<0><<<dim3(24, 64), blk, 0, stream>>>(xb, wqb, qkb, Vt, nullptr, nullptr, 3072, 1024);
    attn<<<dim3(16, 128), blk, 0, stream>>>(qkb, Vt, Ob);
    gemm16<1><<<dim3(8, 64), blk, 0, stream>>>(Ob, wob, nullptr, nullptr, out, b_out, 1024, 1024);
}

// Round 12
// 238.737 us; speedup vs baseline: 1.0386x; 1.0386x over previous
//
#include <hip/hip_runtime.h>

// B=8, L=1024, H=1024, NH=16, HD=64. fp32 I/O, bf16 MFMA internals.
// Pipeline: cvt3     : x,w_qkv,w_out fp32 -> bf16                  (~13 us)
//           gemm16<0>: qk = x@w_qkv^T cols<2048; V scatters to Vt  (51.5 GF)
//           attn     : no-max softmax flash attn, S^T trick        (34.4 GF)
//           gemm16<1>: out = O@w_out^T + b_out (fp32 out)          (17.2 GF)
// R12 (attn): LDS-BW diet. attn was LDS-read-bound (16 ds_read_b128 per 16
// small MFMAs ~ 41 us/CU). Switch to mfma_f32_32x32x16_bf16: same 16B frags,
// 2x MACs -> LDS bytes/MAC halved. Wave owns 32q x 64kv x 64d. Register-P
// trick via K-staging permutation: swap bits 2<->3 of kv row so S^T C-regs
// packed pairwise == PV A-frags (C/D 32x32 layout verified m74/m101).
// Rowsum = per-lane adds + one shfl_xor(32). Grid (8,128), LDS 16.4 KB.

typedef short s16x8 __attribute__((ext_vector_type(8)));
typedef float f32x4 __attribute__((ext_vector_type(4)));
typedef float f32x16 __attribute__((ext_vector_type(16)));
typedef unsigned int u32x2 __attribute__((ext_vector_type(2)));
typedef unsigned int u32x4 __attribute__((ext_vector_type(4)));

__device__ __forceinline__ unsigned short f2bf(float f) {   // RNE
    union { float f; unsigned u; } c; c.f = f;
    return (unsigned short)((c.u + 0x7FFFu + ((c.u >> 16) & 1u)) >> 16);
}
// pack 2 floats -> 2 bf16 (round-half-up) in 3 VALU ops via v_perm
__device__ __forceinline__ unsigned pack2bf(float a, float b) {
    union { float f; unsigned u; } ca, cb; ca.f = a; cb.f = b;
    return __builtin_amdgcn_perm(cb.u + 0x8000u, ca.u + 0x8000u, 0x07060302u);
}

#define GLOAD_LDS(g, l) __builtin_amdgcn_global_load_lds( \
    (const __attribute__((address_space(1))) void*)(g),   \
    (__attribute__((address_space(3))) void*)(l), 16, 0, 0)

// ---------------------------------------------------------------------------
// fp32 -> bf16 convert for the three input tensors.
// ---------------------------------------------------------------------------
__global__ __launch_bounds__(256) void cvt3(
    const float* __restrict__ s0, unsigned short* __restrict__ d0, int n0,
    const float* __restrict__ s1, unsigned short* __restrict__ d1, int n1,
    const float* __restrict__ s2, unsigned short* __restrict__ d2, int n2)
{
    long i = ((long)blockIdx.x * 256 + threadIdx.x) * 8;
    const float* s; unsigned short* d; long off;
    if (i < n0)                  { s = s0; d = d0; off = i; }
    else if (i < (long)n0 + n1)  { s = s1; d = d1; off = i - n0; }
    else                         { s = s2; d = d2; off = i - n0 - n1; }
    f32x4 a = *(const f32x4*)(s + off);
    f32x4 b = *(const f32x4*)(s + off + 4);
    u32x4 r;
    r[0] = pack2bf(a[0], a[1]); r[1] = pack2bf(a[2], a[3]);
    r[2] = pack2bf(b[0], b[1]); r[3] = pack2bf(b[2], b[3]);
    *(u32x4*)(d + off) = r;
}

// ---------------------------------------------------------------------------
// GEMM: C[M,N] = A[M,K]*B[N,K]^T, bf16 in, fp32 accum. 128x128 tile, BK=64,
// global_load_lds dwordx4. LDS [128][64] elems, XOR swizzle: logical 16B
// chunk q of row r at physical chunk q ^ (r&7) -> 2-way on banks (free).
// EPI=0: cols<1024 (Q) -> Cq bf16 scaled by 0.125*log2(e) (softmax prefold);
//        cols 1024..2047 (K) -> Cq bf16 unscaled; cols>=2048 (V) packed-
//        scatter to Cv = Vt[(b*16+h)*64+d][l] bf16.
// EPI=1: Cf fp32 + bias.
// ---------------------------------------------------------------------------
template<int EPI>
__global__ __launch_bounds__(256) void gemm16(
    const unsigned short* __restrict__ A, const unsigned short* __restrict__ Bm,
    unsigned short* __restrict__ Cq, unsigned short* __restrict__ Cv,
    float* __restrict__ Cf, const float* __restrict__ bias,
    int N, int K)
{
    __shared__ unsigned short As[128 * 64];
    __shared__ unsigned short Bs[128 * 64];
    const int tid = threadIdx.x, lane = tid & 63, wave = tid >> 6;
    const int quad = lane >> 4, l16 = lane & 15;
    const int wm = (wave >> 1) * 64, wn = (wave & 1) * 64;
    const int m0 = blockIdx.y * 128, n0 = blockIdx.x * 128;

    const int prow = tid >> 3;
    const int qch  = (tid & 7) ^ (prow & 7);
    const unsigned short* gA[4];
    const unsigned short* gB[4];
    #pragma unroll
    for (int c = 0; c < 4; ++c) {
        gA[c] = A + (size_t)(m0 + c * 32 + prow) * K + qch * 8;
        gB[c] = Bm + (size_t)(n0 + c * 32 + prow) * K + qch * 8;
    }
    const int sw = l16 & 7;   // frag-read swizzle

    f32x4 acc[4][4] = {};
    for (int k0 = 0; k0 < K; k0 += 64) {
        __syncthreads();
        #pragma unroll
        for (int c = 0; c < 4; ++c) {
            GLOAD_LDS(gA[c], As + (c * 256 + tid) * 8);
            GLOAD_LDS(gB[c], Bs + (c * 256 + tid) * 8);
            gA[c] += 64; gB[c] += 64;
        }
        __syncthreads();
        #pragma unroll
        for (int s = 0; s < 2; ++s) {
            s16x8 af[4], bf[4];
            const int pc = ((s * 4 + quad) ^ sw) * 8;
            #pragma unroll
            for (int i = 0; i < 4; ++i)
                af[i] = *(const s16x8*)(As + (wm + i * 16 + l16) * 64 + pc);
            #pragma unroll
            for (int j = 0; j < 4; ++j)
                bf[j] = *(const s16x8*)(Bs + (wn + j * 16 + l16) * 64 + pc);
            #pragma unroll
            for (int i = 0; i < 4; ++i)
                #pragma unroll
                for (int j = 0; j < 4; ++j)
                    acc[i][j] = __builtin_amdgcn_mfma_f32_16x16x32_bf16(af[i], bf[j], acc[i][j], 0, 0, 0);
        }
    }

    // epilogue: C/D layout col=lane&15, row=quad*4+reg
    if (EPI == 1) {
        #pragma unroll
        for (int j = 0; j < 4; ++j) {
            int col = n0 + wn + j * 16 + l16;
            float bv = bias[col];
            #pragma unroll
            for (int i = 0; i < 4; ++i)
                #pragma unroll
                for (int r = 0; r < 4; ++r)
                    Cf[(size_t)(m0 + wm + i * 16 + quad * 4 + r) * N + col] = acc[i][j][r] + bv;
        }
    } else if (n0 < 2048) {
        // Q region: prefold softmax scale (1/8) and log2(e) for native exp2
        const float qs = (n0 < 1024) ? 0.18033688f : 1.0f;   // 0.125*log2(e)
        #pragma unroll
        for (int j = 0; j < 4; ++j) {
            int col = n0 + wn + j * 16 + l16;
            #pragma unroll
            for (int i = 0; i < 4; ++i)
                #pragma unroll
                for (int r = 0; r < 4; ++r)
                    Cq[(size_t)(m0 + wm + i * 16 + quad * 4 + r) * 2048 + col] = f2bf(acc[i][j][r] * qs);
        }
    } else {
        // V region: lane's r=0..3 are 4 consecutive l -> one 8B packed store
        #pragma unroll
        for (int j = 0; j < 4; ++j) {
            int dcol = n0 + wn + j * 16 + l16 - 2048;
            int hh = dcol >> 6, dd = dcol & 63;
            #pragma unroll
            for (int i = 0; i < 4; ++i) {
                int row = m0 + wm + i * 16 + quad * 4;
                int bb = row >> 10, l = row & 1023;
                u32x2 pw;
                pw[0] = pack2bf(acc[i][j][0], acc[i][j][1]);
                pw[1] = pack2bf(acc[i][j][2], acc[i][j][3]);
                *(u32x2*)(Cv + (size_t)((bb * 16 + hh) * 64 + dd) * 1024 + l) = pw;
            }
        }
    }
}

// ---------------------------------------------------------------------------
// Flash attention, 32x32x16 MFMA edition.
// Block = 128 q-rows, 4 waves x 32 q each; K/V tiles 64kv x 64d in LDS.
// K staging permutation: LDS row rho holds kv = swap_bits_2_3(rho) so that
// S^T (A=K,B=Q) C-layout regs, packed pairwise, are the PV A-frags:
//   C row(reg r, h) = (r&3)+8*(r>>2)+4h; with r=8c+j this row's kv
//   = 16c+8h+j  == A-frag element j of kv-chunk c. (C/D layout m74/m101.)
// Rowsum: per-lane adds over 32 regs (q = lane&31) + shfl_xor(32).
// Grid (8 qtile, 128 bh) = 1024 blocks = 4/CU. LDS 16.4 KB.
// ---------------------------------------------------------------------------
__global__ __launch_bounds__(256) void attn(
    const unsigned short* __restrict__ qk, const unsigned short* __restrict__ Vt,
    unsigned short* __restrict__ O)
{
    __shared__ unsigned short Ks[64 * 64];   // [rho][d], kv-bit-swapped, chunk-swizzled
    __shared__ unsigned short Vs[64 * 64];   // [d][kv],  natural rows, chunk-swizzled

    const int bh = blockIdx.y, b = bh >> 4, hh = bh & 15;
    const int q0 = blockIdx.x * 128;
    const int tid = threadIdx.x, lane = tid & 63, wave = tid >> 6;
    const int l31 = lane & 31, hf = lane >> 5;

    // Q B-frags from global (loop-invariant): n=q=wave*32+l31, k=d=16c+8*hf+j
    const unsigned short* qrow =
        qk + (size_t)(b * 1024 + q0 + wave * 32 + l31) * 2048 + hh * 64;
    s16x8 qf[4];
    #pragma unroll
    for (int c = 0; c < 4; ++c)
        qf[c] = *(const s16x8*)(qrow + c * 16 + hf * 8);

    // Staging: 2 chunks each for K and V per thread.
    // chunk i: lin = tid + i*256 -> LDS row = lin>>3, phys chunk = lin&7,
    // logical chunk qc = (lin&7) ^ (row&7). K's global kv row = swap bits2,3 of row.
    const int r0 = tid >> 3,        p0 = tid & 7;
    const int r1 = r0 + 32,         p1 = p0;
    const int qc0 = p0 ^ (r0 & 7),  qc1 = p1 ^ (r1 & 7);
    const int kvp0 = (r0 & ~12) | ((r0 & 4) << 1) | ((r0 & 8) >> 1);
    const int kvp1 = (r1 & ~12) | ((r1 & 4) << 1) | ((r1 & 8) >> 1);
    const unsigned short* srcK0 = qk + (size_t)(b * 1024 + kvp0) * 2048 + 1024 + hh * 64 + qc0 * 8;
    const unsigned short* srcK1 = qk + (size_t)(b * 1024 + kvp1) * 2048 + 1024 + hh * 64 + qc1 * 8;
    const unsigned short* srcV0 = Vt + (size_t)(bh * 64 + r0) * 1024 + qc0 * 8;
    const unsigned short* srcV1 = Vt + (size_t)(bh * 64 + r1) * 1024 + qc1 * 8;
    unsigned short* dK0 = Ks + r0 * 64 + p0 * 8;
    unsigned short* dK1 = Ks + r1 * 64 + p1 * 8;
    unsigned short* dV0 = Vs + r0 * 64 + p0 * 8;
    unsigned short* dV1 = Vs + r1 * 64 + p1 * 8;

    const int sw = l31 & 7;   // frag-read swizzle

    f32x16 Oacc[2] = {};      // d-tiles 0,1 (32 d each)
    float lsum = 0.0f;

    for (int kv = 0; kv < 1024; kv += 64) {
        __syncthreads();
        GLOAD_LDS(srcK0, dK0);
        GLOAD_LDS(srcK1, dK1);
        GLOAD_LDS(srcV0, dV0);
        GLOAD_LDS(srcV1, dV1);
        srcK0 += (size_t)64 * 2048; srcK1 += (size_t)64 * 2048;
        srcV0 += 64; srcV1 += 64;
        __syncthreads();   // vmcnt(0) drain -> K,V in LDS

        // S^T = K Q^T : two 32-kv tiles, A rows = permuted LDS rows, B = Q
        f32x16 Sacc[2] = {};
        #pragma unroll
        for (int c = 0; c < 4; ++c) {
            #pragma unroll
            for (int t = 0; t < 2; ++t) {
                s16x8 kf = *(const s16x8*)(Ks + (t * 32 + l31) * 64 + ((2 * c + hf) ^ sw) * 8);
                Sacc[t] = __builtin_amdgcn_mfma_f32_32x32x16_bf16(kf, qf[c], Sacc[t], 0, 0, 0);
            }
        }
        // p = 2^s (scale prefolded into Q); per-lane rowsum (q = l31); pack
        unsigned upw[2][8];
        #pragma unroll
        for (int t = 0; t < 2; ++t)
            #pragma unroll
            for (int i = 0; i < 8; ++i) {
                float pa = __builtin_amdgcn_exp2f(Sacc[t][2 * i]);
                float pb = __builtin_amdgcn_exp2f(Sacc[t][2 * i + 1]);
                lsum += pa + pb;
                upw[t][i] = pack2bf(pa, pb);
            }
        // O += P V^T : A = packed C-regs (kv-chunk c = tile c>>1, half c&1)
        #pragma unroll
        for (int c = 0; c < 4; ++c) {
            u32x4 aw;
            aw[0] = upw[c >> 1][4 * (c & 1) + 0];
            aw[1] = upw[c >> 1][4 * (c & 1) + 1];
            aw[2] = upw[c >> 1][4 * (c & 1) + 2];
            aw[3] = upw[c >> 1][4 * (c & 1) + 3];
            s16x8 pf;
            __builtin_memcpy(&pf, &aw, 16);
            #pragma unroll
            for (int dt = 0; dt < 2; ++dt) {
                s16x8 vf = *(const s16x8*)(Vs + (dt * 32 + l31) * 64 + ((2 * c + hf) ^ sw) * 8);
                Oacc[dt] = __builtin_amdgcn_mfma_f32_32x32x16_bf16(pf, vf, Oacc[dt], 0, 0, 0);
            }
        }
    }

    // rowsum finalize: halves (l31, l31+32) together cover all kv rows
    lsum += __shfl_xor(lsum, 32, 64);   // total for q = wave*32 + l31

    // normalize + write: O C-layout col=d=l31(+32*dt), row q_r=(r&3)+8*(r>>2)+4*hf
    #pragma unroll
    for (int r = 0; r < 16; ++r) {
        int q_r = (r & 3) + 8 * (r >> 2) + 4 * hf;
        float rinv = 1.0f / __shfl(lsum, q_r, 64);
        int row = b * 1024 + q0 + wave * 32 + q_r;
        #pragma unroll
        for (int dt = 0; dt < 2; ++dt) {
            int col = hh * 64 + dt * 32 + l31;
            O[(size_t)row * 1024 + col] = f2bf(Oacc[dt][r] * rinv);
        }
    }
}

extern "C" void kernel_launch(void* const* d_in, const int* in_sizes, int n_in,
                              void* d_out, int out_size, void* d_ws, size_t ws_size,
                              hipStream_t stream) {
    const float* x     = (const float*)d_in[0];   // [8192,1024]
    const float* w_qkv = (const float*)d_in[1];   // [3072,1024]
    const float* w_out = (const float*)d_in[2];   // [1024,1024]
    const float* b_out = (const float*)d_in[3];   // [1024]
    float* out = (float*)d_out;                   // [8192,1024] fp32

    const int nx = 8192 * 1024, nwq = 3072 * 1024, nwo = 1024 * 1024;
    unsigned short* xb  = (unsigned short*)d_ws;          // 16.8 MB (dead after gemm1)
    unsigned short* wqb = xb + nx;                        //  6.3 MB
    unsigned short* wob = wqb + nwq;                      //  2.1 MB
    unsigned short* qkb = wob + nwo;                      // [8192,2048] Q|K, 33.6 MB
    unsigned short* Vt  = qkb + (size_t)8192 * 2048;      // [128*64,1024], 16.8 MB
    unsigned short* Ob  = xb;                             // alias: xb dead after gemm1

    dim3 blk(256);
    cvt3<<<6144, blk, 0, stream>>>(x, xb, nx, w_qkv, wqb, nwq, w_out, wob, nwo);
    gemm16<0><<<dim3(24, 64), blk, 0, stream>>>(xb, wqb, qkb, Vt, nullptr, nullptr, 3072, 1024);
    attn<<<dim3(8, 128), blk, 0, stream>>>(qkb, Vt, Ob);
    gemm16<1><<<dim3(8, 64), blk, 0, stream>>>(Ob, wob, nullptr, nullptr, out, b_out, 1024, 1024);
}

// Round 13
// 238.283 us; speedup vs baseline: 1.0406x; 1.0019x over previous
//
#include <hip/hip_runtime.h>

// B=8, L=1024, H=1024, NH=16, HD=64. fp32 I/O, bf16 MFMA internals.
// Pipeline: cvt3     : x,w_qkv,w_out fp32 -> bf16                  (~13 us)
//           gemm16<0>: qk = x@w_qkv^T cols<2048; V scatters to Vt  (51.5 GF)
//           attn     : no-max softmax flash attn, S^T trick        (34.4 GF)
//           gemm16<1>: out = O@w_out^T + b_out (fp32 out)          (17.2 GF)
// R13 (attn): R12's 32x32x16 MFMA kept (halves LDS bytes/MAC) but the LDS
// layout gains an 8-row GROUP PAD (group stride 1040 B = 1 KB data + 16 B):
// bank = ((row>>3)+chunk)*4+word, so the 4 lanes sharing a chunk (which made
// R12 4-way-conflicted, since 128 B row stride never touches banks) now hit
// distinct bank-quads -> optimal wave64 b128 distribution. Staging stays
// global_load_lds-legal: group base is wave-uniform, lanes write +lane*16.

typedef short s16x8 __attribute__((ext_vector_type(8)));
typedef float f32x4 __attribute__((ext_vector_type(4)));
typedef float f32x16 __attribute__((ext_vector_type(16)));
typedef unsigned int u32x2 __attribute__((ext_vector_type(2)));
typedef unsigned int u32x4 __attribute__((ext_vector_type(4)));

__device__ __forceinline__ unsigned short f2bf(float f) {   // RNE
    union { float f; unsigned u; } c; c.f = f;
    return (unsigned short)((c.u + 0x7FFFu + ((c.u >> 16) & 1u)) >> 16);
}
// pack 2 floats -> 2 bf16 (round-half-up) in 3 VALU ops via v_perm
__device__ __forceinline__ unsigned pack2bf(float a, float b) {
    union { float f; unsigned u; } ca, cb; ca.f = a; cb.f = b;
    return __builtin_amdgcn_perm(cb.u + 0x8000u, ca.u + 0x8000u, 0x07060302u);
}

#define GLOAD_LDS(g, l) __builtin_amdgcn_global_load_lds( \
    (const __attribute__((address_space(1))) void*)(g),   \
    (__attribute__((address_space(3))) void*)(l), 16, 0, 0)

// ---------------------------------------------------------------------------
// fp32 -> bf16 convert for the three input tensors.
// ---------------------------------------------------------------------------
__global__ __launch_bounds__(256) void cvt3(
    const float* __restrict__ s0, unsigned short* __restrict__ d0, int n0,
    const float* __restrict__ s1, unsigned short* __restrict__ d1, int n1,
    const float* __restrict__ s2, unsigned short* __restrict__ d2, int n2)
{
    long i = ((long)blockIdx.x * 256 + threadIdx.x) * 8;
    const float* s; unsigned short* d; long off;
    if (i < n0)                  { s = s0; d = d0; off = i; }
    else if (i < (long)n0 + n1)  { s = s1; d = d1; off = i - n0; }
    else                         { s = s2; d = d2; off = i - n0 - n1; }
    f32x4 a = *(const f32x4*)(s + off);
    f32x4 b = *(const f32x4*)(s + off + 4);
    u32x4 r;
    r[0] = pack2bf(a[0], a[1]); r[1] = pack2bf(a[2], a[3]);
    r[2] = pack2bf(b[0], b[1]); r[3] = pack2bf(b[2], b[3]);
    *(u32x4*)(d + off) = r;
}

// ---------------------------------------------------------------------------
// GEMM: C[M,N] = A[M,K]*B[N,K]^T, bf16 in, fp32 accum. 128x128 tile, BK=64,
// global_load_lds dwordx4. LDS [128][64] elems, XOR swizzle: logical 16B
// chunk q of row r at physical chunk q ^ (r&7) -> 2-way on banks (free).
// EPI=0: cols<1024 (Q) -> Cq bf16 scaled by 0.125*log2(e) (softmax prefold);
//        cols 1024..2047 (K) -> Cq bf16 unscaled; cols>=2048 (V) packed-
//        scatter to Cv = Vt[(b*16+h)*64+d][l] bf16.
// EPI=1: Cf fp32 + bias.
// ---------------------------------------------------------------------------
template<int EPI>
__global__ __launch_bounds__(256) void gemm16(
    const unsigned short* __restrict__ A, const unsigned short* __restrict__ Bm,
    unsigned short* __restrict__ Cq, unsigned short* __restrict__ Cv,
    float* __restrict__ Cf, const float* __restrict__ bias,
    int N, int K)
{
    __shared__ unsigned short As[128 * 64];
    __shared__ unsigned short Bs[128 * 64];
    const int tid = threadIdx.x, lane = tid & 63, wave = tid >> 6;
    const int quad = lane >> 4, l16 = lane & 15;
    const int wm = (wave >> 1) * 64, wn = (wave & 1) * 64;
    const int m0 = blockIdx.y * 128, n0 = blockIdx.x * 128;

    const int prow = tid >> 3;
    const int qch  = (tid & 7) ^ (prow & 7);
    const unsigned short* gA[4];
    const unsigned short* gB[4];
    #pragma unroll
    for (int c = 0; c < 4; ++c) {
        gA[c] = A + (size_t)(m0 + c * 32 + prow) * K + qch * 8;
        gB[c] = Bm + (size_t)(n0 + c * 32 + prow) * K + qch * 8;
    }
    const int sw = l16 & 7;   // frag-read swizzle

    f32x4 acc[4][4] = {};
    for (int k0 = 0; k0 < K; k0 += 64) {
        __syncthreads();
        #pragma unroll
        for (int c = 0; c < 4; ++c) {
            GLOAD_LDS(gA[c], As + (c * 256 + tid) * 8);
            GLOAD_LDS(gB[c], Bs + (c * 256 + tid) * 8);
            gA[c] += 64; gB[c] += 64;
        }
        __syncthreads();
        #pragma unroll
        for (int s = 0; s < 2; ++s) {
            s16x8 af[4], bf[4];
            const int pc = ((s * 4 + quad) ^ sw) * 8;
            #pragma unroll
            for (int i = 0; i < 4; ++i)
                af[i] = *(const s16x8*)(As + (wm + i * 16 + l16) * 64 + pc);
            #pragma unroll
            for (int j = 0; j < 4; ++j)
                bf[j] = *(const s16x8*)(Bs + (wn + j * 16 + l16) * 64 + pc);
            #pragma unroll
            for (int i = 0; i < 4; ++i)
                #pragma unroll
                for (int j = 0; j < 4; ++j)
                    acc[i][j] = __builtin_amdgcn_mfma_f32_16x16x32_bf16(af[i], bf[j], acc[i][j], 0, 0, 0);
        }
    }

    // epilogue: C/D layout col=lane&15, row=quad*4+reg
    if (EPI == 1) {
        #pragma unroll
        for (int j = 0; j < 4; ++j) {
            int col = n0 + wn + j * 16 + l16;
            float bv = bias[col];
            #pragma unroll
            for (int i = 0; i < 4; ++i)
                #pragma unroll
                for (int r = 0; r < 4; ++r)
                    Cf[(size_t)(m0 + wm + i * 16 + quad * 4 + r) * N + col] = acc[i][j][r] + bv;
        }
    } else if (n0 < 2048) {
        // Q region: prefold softmax scale (1/8) and log2(e) for native exp2
        const float qs = (n0 < 1024) ? 0.18033688f : 1.0f;   // 0.125*log2(e)
        #pragma unroll
        for (int j = 0; j < 4; ++j) {
            int col = n0 + wn + j * 16 + l16;
            #pragma unroll
            for (int i = 0; i < 4; ++i)
                #pragma unroll
                for (int r = 0; r < 4; ++r)
                    Cq[(size_t)(m0 + wm + i * 16 + quad * 4 + r) * 2048 + col] = f2bf(acc[i][j][r] * qs);
        }
    } else {
        // V region: lane's r=0..3 are 4 consecutive l -> one 8B packed store
        #pragma unroll
        for (int j = 0; j < 4; ++j) {
            int dcol = n0 + wn + j * 16 + l16 - 2048;
            int hh = dcol >> 6, dd = dcol & 63;
            #pragma unroll
            for (int i = 0; i < 4; ++i) {
                int row = m0 + wm + i * 16 + quad * 4;
                int bb = row >> 10, l = row & 1023;
                u32x2 pw;
                pw[0] = pack2bf(acc[i][j][0], acc[i][j][1]);
                pw[1] = pack2bf(acc[i][j][2], acc[i][j][3]);
                *(u32x2*)(Cv + (size_t)((bb * 16 + hh) * 64 + dd) * 1024 + l) = pw;
            }
        }
    }
}

// ---------------------------------------------------------------------------
// Flash attention, 32x32x16 MFMA, group-padded LDS (conflict-free b128).
// LDS layout: 8-row groups, group stride 520 shorts (1040 B = 1 KB + 16 B pad);
// addr(row, pchunk) = (row>>3)*520 + (row&7)*64 + pchunk*8.
// Chunk swizzle: logical chunk q of row r stored at physical q ^ (r&7).
// K staging permutation: LDS row rho holds kv = swap_bits_2_3(rho) so that
// S^T (A=K,B=Q) C-layout regs, packed pairwise, are the PV A-frags (m74/m101).
// Block = 128 q-rows, 4 waves x 32 q. Grid (8 qtile, 128 bh). LDS 16.6 KB.
// ---------------------------------------------------------------------------
#define AGRP 520   // shorts per 8-row group

__global__ __launch_bounds__(256) void attn(
    const unsigned short* __restrict__ qk, const unsigned short* __restrict__ Vt,
    unsigned short* __restrict__ O)
{
    __shared__ unsigned short Ks[8 * AGRP];   // [rho][d], kv-bit-swapped
    __shared__ unsigned short Vs[8 * AGRP];   // [d][kv],  natural rows

    const int bh = blockIdx.y, b = bh >> 4, hh = bh & 15;
    const int q0 = blockIdx.x * 128;
    const int tid = threadIdx.x, lane = tid & 63, wave = tid >> 6;
    const int l31 = lane & 31, hf = lane >> 5;

    // Q B-frags from global (loop-invariant): n=q=wave*32+l31, k=d=16c+8*hf+j
    const unsigned short* qrow =
        qk + (size_t)(b * 1024 + q0 + wave * 32 + l31) * 2048 + hh * 64;
    s16x8 qf[4];
    #pragma unroll
    for (int c = 0; c < 4; ++c)
        qf[c] = *(const s16x8*)(qrow + c * 16 + hf * 8);

    // Staging: chunk i covers rows r = i*32 + wave*8 + (lane>>3), pchunk = lane&7.
    // Logical chunk qc = pchunk ^ (row&7) = (lane&7) ^ (lane>>3).
    // K's global kv row = swap bits 2,3 of row. Dest: group (row>>3) base
    // wave-uniform + lane*16 B (global_load_lds-legal).
    const int r0 = wave * 8 + (lane >> 3), r1 = r0 + 32;
    const int qc = (lane & 7) ^ (lane >> 3);
    const int kvp0 = (r0 & ~12) | ((r0 & 4) << 1) | ((r0 & 8) >> 1);
    const int kvp1 = (r1 & ~12) | ((r1 & 4) << 1) | ((r1 & 8) >> 1);
    const unsigned short* srcK0 = qk + (size_t)(b * 1024 + kvp0) * 2048 + 1024 + hh * 64 + qc * 8;
    const unsigned short* srcK1 = qk + (size_t)(b * 1024 + kvp1) * 2048 + 1024 + hh * 64 + qc * 8;
    const unsigned short* srcV0 = Vt + (size_t)(bh * 64 + r0) * 1024 + qc * 8;
    const unsigned short* srcV1 = Vt + (size_t)(bh * 64 + r1) * 1024 + qc * 8;
    unsigned short* dK0 = Ks + wave * AGRP + lane * 8;
    unsigned short* dK1 = Ks + (wave + 4) * AGRP + lane * 8;
    unsigned short* dV0 = Vs + wave * AGRP + lane * 8;
    unsigned short* dV1 = Vs + (wave + 4) * AGRP + lane * 8;

    const int sw = l31 & 7;   // frag-read chunk swizzle

    f32x16 Oacc[2] = {};      // d-tiles 0,1 (32 d each)
    float lsum = 0.0f;

    for (int kv = 0; kv < 1024; kv += 64) {
        __syncthreads();
        GLOAD_LDS(srcK0, dK0);
        GLOAD_LDS(srcK1, dK1);
        GLOAD_LDS(srcV0, dV0);
        GLOAD_LDS(srcV1, dV1);
        srcK0 += (size_t)64 * 2048; srcK1 += (size_t)64 * 2048;
        srcV0 += 64; srcV1 += 64;
        __syncthreads();   // vmcnt(0) drain -> K,V in LDS

        // S^T = K Q^T : two 32-kv tiles; frag at row rho = t*32+l31,
        // logical chunk 2c+hf -> addr (rho>>3)*520 + (rho&7)*64 + ((2c+hf)^sw)*8
        f32x16 Sacc[2] = {};
        #pragma unroll
        for (int c = 0; c < 4; ++c) {
            #pragma unroll
            for (int t = 0; t < 2; ++t) {
                const unsigned short* kp = Ks + (t * 4 + (l31 >> 3)) * AGRP
                                         + (l31 & 7) * 64 + ((2 * c + hf) ^ sw) * 8;
                Sacc[t] = __builtin_amdgcn_mfma_f32_32x32x16_bf16(
                    *(const s16x8*)kp, qf[c], Sacc[t], 0, 0, 0);
            }
        }
        // p = 2^s (scale prefolded into Q); per-lane rowsum (q = l31); pack
        unsigned upw[2][8];
        #pragma unroll
        for (int t = 0; t < 2; ++t)
            #pragma unroll
            for (int i = 0; i < 8; ++i) {
                float pa = __builtin_amdgcn_exp2f(Sacc[t][2 * i]);
                float pb = __builtin_amdgcn_exp2f(Sacc[t][2 * i + 1]);
                lsum += pa + pb;
                upw[t][i] = pack2bf(pa, pb);
            }
        // O += P V^T : A = packed C-regs (kv-chunk c = tile c>>1, half c&1)
        #pragma unroll
        for (int c = 0; c < 4; ++c) {
            u32x4 aw;
            aw[0] = upw[c >> 1][4 * (c & 1) + 0];
            aw[1] = upw[c >> 1][4 * (c & 1) + 1];
            aw[2] = upw[c >> 1][4 * (c & 1) + 2];
            aw[3] = upw[c >> 1][4 * (c & 1) + 3];
            s16x8 pf;
            __builtin_memcpy(&pf, &aw, 16);
            #pragma unroll
            for (int dt = 0; dt < 2; ++dt) {
                const unsigned short* vp = Vs + (dt * 4 + (l31 >> 3)) * AGRP
                                         + (l31 & 7) * 64 + ((2 * c + hf) ^ sw) * 8;
                Oacc[dt] = __builtin_amdgcn_mfma_f32_32x32x16_bf16(
                    pf, *(const s16x8*)vp, Oacc[dt], 0, 0, 0);
            }
        }
    }

    // rowsum finalize: halves (l31, l31+32) together cover all kv rows
    lsum += __shfl_xor(lsum, 32, 64);   // total for q = wave*32 + l31

    // normalize + write: O C-layout col=d=l31(+32*dt), row q_r=(r&3)+8*(r>>2)+4*hf
    #pragma unroll
    for (int r = 0; r < 16; ++r) {
        int q_r = (r & 3) + 8 * (r >> 2) + 4 * hf;
        float rinv = 1.0f / __shfl(lsum, q_r, 64);
        int row = b * 1024 + q0 + wave * 32 + q_r;
        #pragma unroll
        for (int dt = 0; dt < 2; ++dt) {
            int col = hh * 64 + dt * 32 + l31;
            O[(size_t)row * 1024 + col] = f2bf(Oacc[dt][r] * rinv);
        }
    }
}

extern "C" void kernel_launch(void* const* d_in, const int* in_sizes, int n_in,
                              void* d_out, int out_size, void* d_ws, size_t ws_size,
                              hipStream_t stream) {
    const float* x     = (const float*)d_in[0];   // [8192,1024]
    const float* w_qkv = (const float*)d_in[1];   // [3072,1024]
    const float* w_out = (const float*)d_in[2];   // [1024,1024]
    const float* b_out = (const float*)d_in[3];   // [1024]
    float* out = (float*)d_out;                   // [8192,1024] fp32

    const int nx = 8192 * 1024, nwq = 3072 * 1024, nwo = 1024 * 1024;
    unsigned short* xb  = (unsigned short*)d_ws;          // 16.8 MB (dead after gemm1)
    unsigned short* wqb = xb + nx;                        //  6.3 MB
    unsigned short* wob = wqb + nwq;                      //  2.1 MB
    unsigned short* qkb = wob + nwo;                      // [8192,2048] Q|K, 33.6 MB
    unsigned short* Vt  = qkb + (size_t)8192 * 2048;      // [128*64,1024], 16.8 MB
    unsigned short* Ob  = xb;                             // alias: xb dead after gemm1

    dim3 blk(256);
    cvt3<<<6144, blk, 0, stream>>>(x, xb, nx, w_qkv, wqb, nwq, w_out, wob, nwo);
    gemm16<0><<<dim3(24, 64), blk, 0, stream>>>(xb, wqb, qkb, Vt, nullptr, nullptr, 3072, 1024);
    attn<<<dim3(8, 128), blk, 0, stream>>>(qkb, Vt, Ob);
    gemm16<1><<<dim3(8, 64), blk, 0, stream>>>(Ob, wob, nullptr, nullptr, out, b_out, 1024, 1024);
}